// Round 10
// baseline (320.789 us; speedup 1.0000x reference)
//
#include <hip/hip_runtime.h>

typedef __bf16 bf16x8 __attribute__((ext_vector_type(8)));
typedef __bf16 bf16x4 __attribute__((ext_vector_type(4)));
typedef float  f32x4  __attribute__((ext_vector_type(4)));

#define P_  2048
#define D_  4096
#define IC_ 512
#define H_  256
#define R_  5
#define KP_ (R_*D_)   /* 20480 : K for z_p  (r,d) */
#define KD_ (R_*P_)   /* 10240 : K for z_d  (r,p) */

// LDS k-slot swizzle (validated r2-r4)
__device__ __forceinline__ int swzf(int row){ return ((row>>1) ^ (row>>3)) & 3; }

__device__ __forceinline__ bf16x8 cvt8(float4 a, float4 b){
  bf16x8 o;
  o[0]=(__bf16)a.x; o[1]=(__bf16)a.y; o[2]=(__bf16)a.z; o[3]=(__bf16)a.w;
  o[4]=(__bf16)b.x; o[5]=(__bf16)b.y; o[6]=(__bf16)b.z; o[7]=(__bf16)b.w;
  return o;
}

__device__ __forceinline__ void gl_lds16(const __bf16* g, __bf16* l){
  __builtin_amdgcn_global_load_lds(
    (const __attribute__((address_space(1))) unsigned int*)(g),
    (__attribute__((address_space(3))) unsigned int*)(l), 16, 0, 0);
}

// ---------------- K1: fused wcum + prep (r4-validated) ----------------
__global__ __launch_bounds__(256) void k_prep2(const float* __restrict__ S,
    const float* __restrict__ pw, __bf16* __restrict__ Sbf, float* __restrict__ rs,
    float* __restrict__ cspart, __bf16* __restrict__ wct){
  __shared__ float wsum[32][4];
  const int t = threadIdx.x;
  if (blockIdx.x >= 320){
    const int h  = t;
    const int i0 = (blockIdx.x - 320) * 8;
    float acc[8];
    #pragma unroll
    for (int j=0;j<8;++j) acc[j]=0.f;
    for (int r=0;r<R_;++r){
      bf16x8 o;
      #pragma unroll
      for (int j=0;j<8;++j){
        acc[j] += pw[((size_t)r*IC_ + i0 + j)*H_ + h];
        o[j] = (__bf16)acc[j];
      }
      *reinterpret_cast<bf16x8*>(wct + ((size_t)r*H_ + h)*IC_ + i0) = o;
    }
    return;
  }
  const int lane = t & 63, w = t >> 6;
  const int slab = blockIdx.x;
  const int r = slab >> 6, z = slab & 63;
  const size_t row0 = (size_t)r*P_ + (size_t)z*32;
  const float4* src = reinterpret_cast<const float4*>(S + row0*D_);
  __bf16* dst = Sbf + row0*D_;
  f32x4 ca[4];
  #pragma unroll
  for (int c=0;c<4;++c){ ca[c][0]=0.f; ca[c][1]=0.f; ca[c][2]=0.f; ca[c][3]=0.f; }
  for (int pp=0; pp<32; ++pp){
    float4 v[4];
    #pragma unroll
    for (int c=0;c<4;++c) v[c] = src[(size_t)pp*(D_/4) + t + 256*c];
    float rsum = 0.f;
    #pragma unroll
    for (int c=0;c<4;++c){
      ca[c][0]+=v[c].x; ca[c][1]+=v[c].y; ca[c][2]+=v[c].z; ca[c][3]+=v[c].w;
      rsum += v[c].x+v[c].y+v[c].z+v[c].w;
      bf16x4 o; o[0]=(__bf16)v[c].x; o[1]=(__bf16)v[c].y; o[2]=(__bf16)v[c].z; o[3]=(__bf16)v[c].w;
      *reinterpret_cast<bf16x4*>(dst + (size_t)pp*D_ + (t + 256*c)*4) = o;
    }
    #pragma unroll
    for (int off = 32; off; off >>= 1) rsum += __shfl_xor(rsum, off);
    if (lane == 0) wsum[pp][w] = rsum;
  }
  __syncthreads();
  if (t < 32){
    float s = wsum[t][0]+wsum[t][1]+wsum[t][2]+wsum[t][3];
    rs[row0 + t] = (s > 0.f) ? rsqrtf(s) : 0.f;
  }
  float* o = cspart + ((size_t)z*R_ + r)*D_;
  #pragma unroll
  for (int c=0;c<4;++c) *reinterpret_cast<f32x4*>(o + (t + 256*c)*4) = ca[c];
}

__global__ void k_csfin(const float* __restrict__ cspart, float* __restrict__ cs){
  const int i = blockIdx.x*256 + threadIdx.x;
  float s = 0.f;
  #pragma unroll
  for (int z = 0; z < 64; ++z) s += cspart[(size_t)z*(R_*D_) + i];
  cs[i] = (s > 0.f) ? rsqrtf(s) : 0.f;
}

// ---------------- K5: merged tmp GEMMs (r4 2-barrier form — validated) ----------------
__global__ __launch_bounds__(256) void k_tmp(const float* __restrict__ p_feat,
    const float* __restrict__ d_feat, const float* __restrict__ rs,
    const float* __restrict__ cs, const __bf16* __restrict__ wct,
    __bf16* __restrict__ Tpt, __bf16* __restrict__ Tdt){
  __shared__ __bf16 As[64*40];
  const int t = threadIdx.x, lane = t & 63, w = t >> 6;
  const int mt = blockIdx.x, r = blockIdx.y;
  const bool isp = mt < (P_/64);
  const float* feat  = isp ? p_feat : d_feat;
  const float* scale = isp ? rs : cs;
  __bf16* outT = isp ? Tpt : Tdt;
  const int M  = isp ? P_ : D_;
  const int RM = isp ? KD_ : KP_;
  const int m0 = (isp ? mt : mt - P_/64)*64;
  const int srow = t >> 2, skc = (t & 3)*8;
  f32x4 acc[4][4];
  #pragma unroll
  for (int a=0;a<4;++a)
    #pragma unroll
    for (int b=0;b<4;++b){ acc[a][b][0]=0.f; acc[a][b][1]=0.f; acc[a][b][2]=0.f; acc[a][b][3]=0.f; }

  for (int ks = 0; ks < IC_; ks += 32){
    __syncthreads();
    {
      const float* g = feat + (size_t)(m0+srow)*IC_ + ks + skc;
      float4 a = *(const float4*)g, b = *(const float4*)(g+4);
      *reinterpret_cast<bf16x8*>(&As[srow*40 + skc]) = cvt8(a,b);
    }
    __syncthreads();
    bf16x8 af[4], bfv[4];
    #pragma unroll
    for (int tt=0;tt<4;++tt)
      af[tt] = *reinterpret_cast<const bf16x8*>(&As[(16*tt + (lane&15))*40 + (lane>>4)*8]);
    #pragma unroll
    for (int cc=0;cc<4;++cc)
      bfv[cc] = *reinterpret_cast<const bf16x8*>(wct + ((size_t)r*H_ + w*64 + 16*cc + (lane&15))*IC_ + ks + (lane>>4)*8);
    #pragma unroll
    for (int tt=0;tt<4;++tt)
      #pragma unroll
      for (int cc=0;cc<4;++cc)
        acc[tt][cc] = __builtin_amdgcn_mfma_f32_16x16x32_bf16(af[tt], bfv[cc], acc[tt][cc], 0, 0, 0);
  }
  #pragma unroll
  for (int tt=0;tt<4;++tt){
    const int mb = m0 + 16*tt + ((lane>>4)<<2);
    const float s0 = scale[r*M+mb+0], s1 = scale[r*M+mb+1],
                s2 = scale[r*M+mb+2], s3 = scale[r*M+mb+3];
    #pragma unroll
    for (int cc=0;cc<4;++cc){
      const int hc = (w<<6) + 16*cc + (lane&15);
      bf16x4 v;
      v[0]=(__bf16)(acc[tt][cc][0]*s0); v[1]=(__bf16)(acc[tt][cc][1]*s1);
      v[2]=(__bf16)(acc[tt][cc][2]*s2); v[3]=(__bf16)(acc[tt][cc][3]*s3);
      *reinterpret_cast<bf16x4*>(outT + (size_t)hc*RM + r*M + mb) = v;
    }
  }
}

// ---------------- K6: z GEMM v10 ----------------
// 512 blocks: [0,256)=zp (16 tiles x 16 splits), [256,512)=zd (32 tiles x 8 splits);
// chunk=1280, 40 iters BK=32, 2 blocks/CU.
// zp: A register-direct from Sbf (raw, L2-served x4 reuse); zd: A raw scatter, dbuf LDS.
// B: gl_lds double-buffer. ONE barrier/iter; scale applied via r-boundary acc rescale.
__global__ __launch_bounds__(512, 4) void k_z(const __bf16* __restrict__ Sbf,
    const float* __restrict__ rs, const float* __restrict__ cs,
    const __bf16* __restrict__ Tdt, const __bf16* __restrict__ Tpt,
    float* __restrict__ partP, float* __restrict__ partD){
  __shared__ __bf16 As[2][128*32];   // zd only
  __shared__ __bf16 Bs[2][256*32];
  const int t = threadIdx.x, lane = t & 63, w = t >> 6;
  const int wm = w >> 2, wn = w & 3;
  const int bid = blockIdx.x;
  const bool isp = bid < 256;
  const int tile  = isp ? (bid & 15) : ((bid-256) & 31);
  const int split = isp ? (bid >> 4) : ((bid-256) >> 5);
  const int m0 = tile*128;
  const int kbase = split*1280;
  const __bf16* Bsrc = isp ? Tdt : Tpt;
  const int bstr = isp ? KP_ : KD_;
  const float* sv = isp ? rs : cs;           // per-row scale vector
  const int svdim = isp ? P_ : D_;
  const int rsh = isp ? 12 : 11;
  const int rA = kbase >> rsh;
  const int rB = (kbase + 1279) >> rsh;      // chunk spans at most 2 r's
  const int bidx = (rB > rA) ? ((((rA+1) << rsh) - kbase) >> 5) : 999;
  // B staging (linear gl_lds dest + inverse-swizzled global source)
  const int brow0 = t >> 2, brow1 = 128 + brow0;
  const int bko0 = ((t & 3) ^ swzf(brow0)) * 8;
  const int bko1 = ((t & 3) ^ swzf(brow1)) * 8;
  // zd A-staging (raw transpose scatter)
  const int prow = t >> 4, d8 = (t & 15)*8;
  const int kqw = prow >> 3, koff = prow & 7;

  f32x4 acc[4][4];
  #pragma unroll
  for (int a=0;a<4;++a)
    #pragma unroll
    for (int b=0;b<4;++b){ acc[a][b][0]=0.f; acc[a][b][1]=0.f; acc[a][b][2]=0.f; acc[a][b][3]=0.f; }

  // ---- prologue: stage tile 0 ----
  bf16x8 va;
  if (!isp){
    const int pp = kbase & (P_-1);
    va = *reinterpret_cast<const bf16x8*>(Sbf + ((size_t)rA*P_ + pp + prow)*D_ + m0 + d8);
  }
  gl_lds16(Bsrc + (size_t)brow0*bstr + kbase + bko0, &Bs[0][w*512]);
  gl_lds16(Bsrc + (size_t)brow1*bstr + kbase + bko1, &Bs[0][4096 + w*512]);
  if (!isp){
    #pragma unroll
    for (int j=0;j<8;++j){
      const int rowd = d8 + j;
      As[0][rowd*32 + ((kqw ^ swzf(rowd))<<3) + koff] = va[j];
    }
  }

  int cur = 0;
  for (int i = 0; i < 40; ++i){
    const int kg = kbase + 32*i;
    // own gl_lds/ds ops drained, then all-wave rendezvous: buf[cur] valid,
    // everyone done reading buf[nxt] from iter i-1.
    asm volatile("s_waitcnt vmcnt(0) lgkmcnt(0)" ::: "memory");
    __builtin_amdgcn_s_barrier();
    __builtin_amdgcn_sched_barrier(0);
    // rare (<=1 per block) r-boundary rescale: acc *= sv[rA]/sv[rB] per output row
    if (i == bidx){
      #pragma unroll
      for (int tt=0;tt<4;++tt){
        const int mb = m0 + wm*64 + 16*tt + ((lane>>4)<<2);
        const float4 sa = *(const float4*)(sv + (size_t)rA*svdim + mb);
        const float4 sb = *(const float4*)(sv + (size_t)rB*svdim + mb);
        const float q0 = (sb.x>0.f)?sa.x/sb.x:0.f, q1 = (sb.y>0.f)?sa.y/sb.y:0.f,
                    q2 = (sb.z>0.f)?sa.z/sb.z:0.f, q3 = (sb.w>0.f)?sa.w/sb.w:0.f;
        #pragma unroll
        for (int cc=0;cc<4;++cc){
          acc[tt][cc][0]*=q0; acc[tt][cc][1]*=q1; acc[tt][cc][2]*=q2; acc[tt][cc][3]*=q3;
        }
      }
    }
    const int nxt = cur ^ 1;
    bf16x8 af[4];
    if (isp){
      // A register-direct: issue BEFORE B so in-order vmcnt retires A at vmcnt(2)
      const int r = kg >> 12, dd = kg & (D_-1);
      #pragma unroll
      for (int tt=0;tt<4;++tt)
        af[tt] = *reinterpret_cast<const bf16x8*>(
          Sbf + ((size_t)r*P_ + m0 + wm*64 + 16*tt + (lane&15))*D_ + dd + (lane>>4)*8);
    } else if (i+1 < 40){
      const int kg2 = kg + 32;
      const int r2 = kg2 >> 11, pp2 = kg2 & (P_-1);
      va = *reinterpret_cast<const bf16x8*>(Sbf + ((size_t)r2*P_ + pp2 + prow)*D_ + m0 + d8);
    }
    if (i+1 < 40){
      const int kg2 = kg + 32;
      gl_lds16(Bsrc + (size_t)brow0*bstr + kg2 + bko0, &Bs[nxt][w*512]);
      gl_lds16(Bsrc + (size_t)brow1*bstr + kg2 + bko1, &Bs[nxt][4096 + w*512]);
    }
    // ---- compute on buf[cur] ----
    const int kq = lane >> 4;
    bf16x8 bv[4];
    #pragma unroll
    for (int cc=0;cc<4;++cc){
      const int row = wn*64 + 16*cc + (lane&15);
      bv[cc] = *reinterpret_cast<const bf16x8*>(&Bs[cur][row*32 + ((kq ^ swzf(row))<<3)]);
    }
    if (!isp){
      #pragma unroll
      for (int tt=0;tt<4;++tt){
        const int row = wm*64 + 16*tt + (lane&15);
        af[tt] = *reinterpret_cast<const bf16x8*>(&As[cur][row*32 + ((kq ^ swzf(row))<<3)]);
      }
    }
    #pragma unroll
    for (int tt=0;tt<4;++tt)
      #pragma unroll
      for (int cc=0;cc<4;++cc)
        acc[tt][cc] = __builtin_amdgcn_mfma_f32_16x16x32_bf16(af[tt], bv[cc], acc[tt][cc], 0, 0, 0);
    // ---- write-late: zd scatters next A into buf[nxt] ----
    if (!isp && i+1 < 40){
      #pragma unroll
      for (int j=0;j<8;++j){
        const int rowd = d8 + j;
        As[nxt][rowd*32 + ((kqw ^ swzf(rowd))<<3) + koff] = va[j];
      }
    }
    cur = nxt;
  }

  // final scale by sv[rB] and store partials (reduce unchanged)
  float* o = isp ? (partP + (size_t)split*((size_t)P_*H_))
                 : (partD + (size_t)split*((size_t)D_*H_));
  #pragma unroll
  for (int tt=0;tt<4;++tt){
    const int mb = m0 + wm*64 + 16*tt + ((lane>>4)<<2);
    const float4 sb = *(const float4*)(sv + (size_t)rB*svdim + mb);
    const float s4[4] = {sb.x, sb.y, sb.z, sb.w};
    #pragma unroll
    for (int cc=0;cc<4;++cc){
      const int hc = wn*64 + 16*cc + (lane&15);
      #pragma unroll
      for (int j=0;j<4;++j) o[(size_t)(mb+j)*H_ + hc] = acc[tt][cc][j]*s4[j];
    }
  }
}

// ---------------- K7: merged reduce + bias + LeakyReLU (r4-validated) ----------------
__global__ void k_reduce(const float* __restrict__ partP, const float* __restrict__ partD,
    const float* __restrict__ bias, float* __restrict__ out){
  const int i = (blockIdx.x*256 + threadIdx.x)*4;
  float4 s; s.x=s.y=s.z=s.w=0.f;
  if (i < P_*H_){
    #pragma unroll
    for (int z = 0; z < 16; ++z){
      float4 v = *(const float4*)(partP + (size_t)z*((size_t)P_*H_) + i);
      s.x+=v.x; s.y+=v.y; s.z+=v.z; s.w+=v.w;
    }
  } else {
    const int j = i - P_*H_;
    #pragma unroll
    for (int z = 0; z < 8; ++z){
      float4 v = *(const float4*)(partD + (size_t)z*((size_t)D_*H_) + j);
      s.x+=v.x; s.y+=v.y; s.z+=v.z; s.w+=v.w;
    }
  }
  const float4 b = *(const float4*)(bias + (i & (H_-1)));
  s.x+=b.x; s.y+=b.y; s.z+=b.z; s.w+=b.w;
  s.x = (s.x>=0.f)? s.x : 0.1f*s.x;
  s.y = (s.y>=0.f)? s.y : 0.1f*s.y;
  s.z = (s.z>=0.f)? s.z : 0.1f*s.z;
  s.w = (s.w>=0.f)? s.w : 0.1f*s.w;
  *(float4*)(out + i) = s;
}

extern "C" void kernel_launch(void* const* d_in, const int* in_sizes, int n_in,
                              void* d_out, int out_size, void* d_ws, size_t ws_size,
                              hipStream_t stream){
  (void)in_sizes; (void)n_in; (void)out_size; (void)ws_size;
  const float* p_feat = (const float*)d_in[0];
  const float* d_feat = (const float*)d_in[1];
  const float* S      = (const float*)d_in[4];
  const float* pw     = (const float*)d_in[5];
  const float* bias   = (const float*)d_in[6];
  float* out = (float*)d_out;

  char* ws = (char*)d_ws;
  __bf16* wct    = (__bf16*)(ws + 0);           //  1,310,720
  __bf16* Tdt    = (__bf16*)(ws + 1310720);     // 10,485,760
  __bf16* Tpt    = (__bf16*)(ws + 11796480);    //  5,242,880
  float*  rs     = (float*) (ws + 17039360);    //     40,960
  float*  cs     = (float*) (ws + 17080320);    //     81,920
  float*  cspart = (float*) (ws + 17162240);    //  5,242,880 (64 slices)
  __bf16* Sbf    = (__bf16*)(ws + 22405120);    // 83,886,080
  float*  partP  = (float*) (ws + 106291200);   // 33,554,432 (16 slices)
  float*  partD  = (float*) (ws + 139845632);   // 33,554,432 (8 slices)
                                                // end: 173,400,064

  k_prep2 <<<384, 256, 0, stream>>>(S, pw, Sbf, rs, cspart, wct);
  k_csfin <<<(R_*D_)/256, 256, 0, stream>>>(cspart, cs);
  k_tmp   <<<dim3((P_+D_)/64, R_), 256, 0, stream>>>(p_feat, d_feat, rs, cs, wct, Tpt, Tdt);
  k_z     <<<512, 512, 0, stream>>>(Sbf, rs, cs, Tdt, Tpt, partP, partD);
  k_reduce<<<((P_+D_)*H_)/1024, 256, 0, stream>>>(partP, partD, bias, out);
}

// Round 11
// 187.932 us; speedup vs baseline: 1.7069x; 1.7069x over previous
//
#include <hip/hip_runtime.h>

typedef __bf16 bf16x8 __attribute__((ext_vector_type(8)));
typedef __bf16 bf16x4 __attribute__((ext_vector_type(4)));
typedef float  f32x4  __attribute__((ext_vector_type(4)));

#define P_  2048
#define D_  4096
#define IC_ 512
#define H_  256
#define R_  5
#define KP_ (R_*D_)   /* 20480 : K for z_p  (r,d) */
#define KD_ (R_*P_)   /* 10240 : K for z_d  (r,p) */

// LDS k-slot swizzle (validated r2-r4)
__device__ __forceinline__ int swzf(int row){ return ((row>>1) ^ (row>>3)) & 3; }

__device__ __forceinline__ bf16x8 cvt8(float4 a, float4 b){
  bf16x8 o;
  o[0]=(__bf16)a.x; o[1]=(__bf16)a.y; o[2]=(__bf16)a.z; o[3]=(__bf16)a.w;
  o[4]=(__bf16)b.x; o[5]=(__bf16)b.y; o[6]=(__bf16)b.z; o[7]=(__bf16)b.w;
  return o;
}

__device__ __forceinline__ void gl_lds16(const __bf16* g, __bf16* l){
  __builtin_amdgcn_global_load_lds(
    (const __attribute__((address_space(1))) unsigned int*)(g),
    (__attribute__((address_space(3))) unsigned int*)(l), 16, 0, 0);
}

// ---------------- K1: fused wcum + prep. blocks [0,320): prep slab; [320,384): wcum ----------------
__global__ __launch_bounds__(256) void k_prep2(const float* __restrict__ S,
    const float* __restrict__ pw, __bf16* __restrict__ Sbf, float* __restrict__ rs,
    float* __restrict__ cspart, __bf16* __restrict__ wct){
  __shared__ float wsum[32][4];
  const int t = threadIdx.x;
  if (blockIdx.x >= 320){
    const int h  = t;
    const int i0 = (blockIdx.x - 320) * 8;
    float acc[8];
    #pragma unroll
    for (int j=0;j<8;++j) acc[j]=0.f;
    for (int r=0;r<R_;++r){
      bf16x8 o;
      #pragma unroll
      for (int j=0;j<8;++j){
        acc[j] += pw[((size_t)r*IC_ + i0 + j)*H_ + h];
        o[j] = (__bf16)acc[j];
      }
      *reinterpret_cast<bf16x8*>(wct + ((size_t)r*H_ + h)*IC_ + i0) = o;
    }
    return;
  }
  const int lane = t & 63, w = t >> 6;
  const int slab = blockIdx.x;
  const int r = slab >> 6, z = slab & 63;
  const size_t row0 = (size_t)r*P_ + (size_t)z*32;
  const float4* src = reinterpret_cast<const float4*>(S + row0*D_);
  __bf16* dst = Sbf + row0*D_;
  f32x4 ca[4];
  #pragma unroll
  for (int c=0;c<4;++c){ ca[c][0]=0.f; ca[c][1]=0.f; ca[c][2]=0.f; ca[c][3]=0.f; }
  for (int pp=0; pp<32; ++pp){
    float4 v[4];
    #pragma unroll
    for (int c=0;c<4;++c) v[c] = src[(size_t)pp*(D_/4) + t + 256*c];
    float rsum = 0.f;
    #pragma unroll
    for (int c=0;c<4;++c){
      ca[c][0]+=v[c].x; ca[c][1]+=v[c].y; ca[c][2]+=v[c].z; ca[c][3]+=v[c].w;
      rsum += v[c].x+v[c].y+v[c].z+v[c].w;
      bf16x4 o; o[0]=(__bf16)v[c].x; o[1]=(__bf16)v[c].y; o[2]=(__bf16)v[c].z; o[3]=(__bf16)v[c].w;
      *reinterpret_cast<bf16x4*>(dst + (size_t)pp*D_ + (t + 256*c)*4) = o;
    }
    #pragma unroll
    for (int off = 32; off; off >>= 1) rsum += __shfl_xor(rsum, off);
    if (lane == 0) wsum[pp][w] = rsum;
  }
  __syncthreads();
  if (t < 32){
    float s = wsum[t][0]+wsum[t][1]+wsum[t][2]+wsum[t][3];
    rs[row0 + t] = (s > 0.f) ? rsqrtf(s) : 0.f;
  }
  float* o = cspart + ((size_t)z*R_ + r)*D_;
  #pragma unroll
  for (int c=0;c<4;++c) *reinterpret_cast<f32x4*>(o + (t + 256*c)*4) = ca[c];
}

__global__ void k_csfin(const float* __restrict__ cspart, float* __restrict__ cs){
  const int i = blockIdx.x*256 + threadIdx.x;
  float s = 0.f;
  #pragma unroll
  for (int z = 0; z < 64; ++z) s += cspart[(size_t)z*(R_*D_) + i];
  cs[i] = (s > 0.f) ? rsqrtf(s) : 0.f;
}

// ---------------- K5: merged tmp GEMMs (r4 2-barrier form — validated best) ----------------
__global__ __launch_bounds__(256) void k_tmp(const float* __restrict__ p_feat,
    const float* __restrict__ d_feat, const float* __restrict__ rs,
    const float* __restrict__ cs, const __bf16* __restrict__ wct,
    __bf16* __restrict__ Tpt, __bf16* __restrict__ Tdt){
  __shared__ __bf16 As[64*40];
  const int t = threadIdx.x, lane = t & 63, w = t >> 6;
  const int mt = blockIdx.x, r = blockIdx.y;
  const bool isp = mt < (P_/64);
  const float* feat  = isp ? p_feat : d_feat;
  const float* scale = isp ? rs : cs;
  __bf16* outT = isp ? Tpt : Tdt;
  const int M  = isp ? P_ : D_;
  const int RM = isp ? KD_ : KP_;
  const int m0 = (isp ? mt : mt - P_/64)*64;
  const int srow = t >> 2, skc = (t & 3)*8;
  f32x4 acc[4][4];
  #pragma unroll
  for (int a=0;a<4;++a)
    #pragma unroll
    for (int b=0;b<4;++b){ acc[a][b][0]=0.f; acc[a][b][1]=0.f; acc[a][b][2]=0.f; acc[a][b][3]=0.f; }

  for (int ks = 0; ks < IC_; ks += 32){
    __syncthreads();
    {
      const float* g = feat + (size_t)(m0+srow)*IC_ + ks + skc;
      float4 a = *(const float4*)g, b = *(const float4*)(g+4);
      *reinterpret_cast<bf16x8*>(&As[srow*40 + skc]) = cvt8(a,b);
    }
    __syncthreads();
    bf16x8 af[4], bfv[4];
    #pragma unroll
    for (int tt=0;tt<4;++tt)
      af[tt] = *reinterpret_cast<const bf16x8*>(&As[(16*tt + (lane&15))*40 + (lane>>4)*8]);
    #pragma unroll
    for (int cc=0;cc<4;++cc)
      bfv[cc] = *reinterpret_cast<const bf16x8*>(wct + ((size_t)r*H_ + w*64 + 16*cc + (lane&15))*IC_ + ks + (lane>>4)*8);
    #pragma unroll
    for (int tt=0;tt<4;++tt)
      #pragma unroll
      for (int cc=0;cc<4;++cc)
        acc[tt][cc] = __builtin_amdgcn_mfma_f32_16x16x32_bf16(af[tt], bfv[cc], acc[tt][cc], 0, 0, 0);
  }
  #pragma unroll
  for (int tt=0;tt<4;++tt){
    const int mb = m0 + 16*tt + ((lane>>4)<<2);
    const float s0 = scale[r*M+mb+0], s1 = scale[r*M+mb+1],
                s2 = scale[r*M+mb+2], s3 = scale[r*M+mb+3];
    #pragma unroll
    for (int cc=0;cc<4;++cc){
      const int hc = (w<<6) + 16*cc + (lane&15);
      bf16x4 v;
      v[0]=(__bf16)(acc[tt][cc][0]*s0); v[1]=(__bf16)(acc[tt][cc][1]*s1);
      v[2]=(__bf16)(acc[tt][cc][2]*s2); v[3]=(__bf16)(acc[tt][cc][3]*s3);
      *reinterpret_cast<bf16x4*>(outT + (size_t)hc*RM + r*M + mb) = v;
    }
  }
}

// ---------------- K6: merged z GEMM — r4-EXACT structure (measured best) + XCD bid remap ----------------
// 512 blocks: [0,256)=zp (16 tiles x 16 splits), [256,512)=zd (32 tiles x 8 splits).
// Remap bid=(blockIdx&7)*64+blockIdx/8: blocks sharing a B-panel (same split)
// co-locate on one XCD -> B slices (<=2.6MB) L2-resident instead of L3-served.
__global__ __launch_bounds__(512, 4) void k_z(const __bf16* __restrict__ Sbf,
    const float* __restrict__ rs, const float* __restrict__ cs,
    const __bf16* __restrict__ Tdt, const __bf16* __restrict__ Tpt,
    float* __restrict__ partP, float* __restrict__ partD){
  __shared__ __bf16 As[128*32];   // swizzled [row][slot*8+off]
  __shared__ __bf16 Bs[256*32];
  const int t = threadIdx.x, lane = t & 63, w = t >> 6;
  const int wm = w >> 2, wn = w & 3;
  const int bid = ((blockIdx.x & 7) << 6) | (blockIdx.x >> 3);  // bijective, 512=8*64
  const bool isp = bid < 256;
  const int tile  = isp ? (bid & 15) : ((bid-256) & 31);
  const int split = isp ? (bid >> 4) : ((bid-256) >> 5);
  const int m0 = tile*128;
  const int kbase = split*1280;
  const __bf16* Bsrc = isp ? Tdt : Tpt;
  const int bstr = isp ? KP_ : KD_;
  // zp A-staging indices
  const int arow  = t >> 2;
  const int aslot = (t & 3) ^ swzf(arow);
  // zd A-staging indices
  const int prow = t >> 4, d8 = (t & 15)*8;
  // B-staging (common)
  const int brow0 = t >> 2, brow1 = 128 + brow0;
  const int bko0 = ((t & 3) ^ swzf(brow0)) * 8;
  const int bko1 = ((t & 3) ^ swzf(brow1)) * 8;
  __bf16* bdst0 = Bs + w*512;
  __bf16* bdst1 = Bs + 4096 + w*512;
  f32x4 acc[4][4];
  #pragma unroll
  for (int a=0;a<4;++a)
    #pragma unroll
    for (int b=0;b<4;++b){ acc[a][b][0]=0.f; acc[a][b][1]=0.f; acc[a][b][2]=0.f; acc[a][b][3]=0.f; }

  for (int ko = 0; ko < 1280; ko += 32){
    const int kg = kbase + ko;
    __syncthreads();
    if (isp){
      const int r = kg >> 12, dd = kg & (D_-1);   // 32-step never straddles r
      const __bf16* g = Sbf + ((size_t)r*P_ + m0 + arow)*D_ + dd + (t&3)*8;
      const float sc = rs[r*P_ + m0 + arow];
      bf16x8 v = *reinterpret_cast<const bf16x8*>(g);
      bf16x8 o;
      #pragma unroll
      for (int j=0;j<8;++j) o[j] = (__bf16)((float)v[j] * sc);
      *reinterpret_cast<bf16x8*>(&As[arow*32 + aslot*8]) = o;
    } else {
      const int r = kg >> 11, pp = kg & (P_-1);
      const __bf16* g = Sbf + ((size_t)r*P_ + pp + prow)*D_ + m0 + d8;
      bf16x8 v = *reinterpret_cast<const bf16x8*>(g);
      const float4 c1 = *(const float4*)(cs + r*D_ + m0 + d8);
      const float4 c2 = *(const float4*)(cs + r*D_ + m0 + d8 + 4);
      bf16x8 o;
      o[0]=(__bf16)((float)v[0]*c1.x); o[1]=(__bf16)((float)v[1]*c1.y);
      o[2]=(__bf16)((float)v[2]*c1.z); o[3]=(__bf16)((float)v[3]*c1.w);
      o[4]=(__bf16)((float)v[4]*c2.x); o[5]=(__bf16)((float)v[5]*c2.y);
      o[6]=(__bf16)((float)v[6]*c2.z); o[7]=(__bf16)((float)v[7]*c2.w);
      const int kqw = prow >> 3, koff = prow & 7;
      #pragma unroll
      for (int j=0;j<8;++j){
        const int rowd = d8 + j;
        As[rowd*32 + ((kqw ^ swzf(rowd))<<3) + koff] = o[j];
      }
    }
    gl_lds16(Bsrc + (size_t)brow0*bstr + kg + bko0, bdst0);
    gl_lds16(Bsrc + (size_t)brow1*bstr + kg + bko1, bdst1);
    __syncthreads();
    const int kq = lane >> 4;
    bf16x8 bv[4];
    #pragma unroll
    for (int cc=0;cc<4;++cc){
      const int row = wn*64 + 16*cc + (lane&15);
      bv[cc] = *reinterpret_cast<const bf16x8*>(&Bs[row*32 + ((kq ^ swzf(row))<<3)]);
    }
    #pragma unroll
    for (int tt=0;tt<4;++tt){
      const int row = wm*64 + 16*tt + (lane&15);
      bf16x8 af = *reinterpret_cast<const bf16x8*>(&As[row*32 + ((kq ^ swzf(row))<<3)]);
      #pragma unroll
      for (int cc=0;cc<4;++cc)
        acc[tt][cc] = __builtin_amdgcn_mfma_f32_16x16x32_bf16(af, bv[cc], acc[tt][cc], 0, 0, 0);
    }
  }
  float* o = isp ? (partP + (size_t)split*((size_t)P_*H_))
                 : (partD + (size_t)split*((size_t)D_*H_));
  #pragma unroll
  for (int tt=0;tt<4;++tt){
    const int mb = m0 + wm*64 + 16*tt + ((lane>>4)<<2);
    #pragma unroll
    for (int cc=0;cc<4;++cc){
      const int hc = wn*64 + 16*cc + (lane&15);
      #pragma unroll
      for (int j=0;j<4;++j) o[(size_t)(mb+j)*H_ + hc] = acc[tt][cc][j];
    }
  }
}

// ---------------- K7: merged reduce + bias + LeakyReLU (r4-validated) ----------------
__global__ void k_reduce(const float* __restrict__ partP, const float* __restrict__ partD,
    const float* __restrict__ bias, float* __restrict__ out){
  const int i = (blockIdx.x*256 + threadIdx.x)*4;
  float4 s; s.x=s.y=s.z=s.w=0.f;
  if (i < P_*H_){
    #pragma unroll
    for (int z = 0; z < 16; ++z){
      float4 v = *(const float4*)(partP + (size_t)z*((size_t)P_*H_) + i);
      s.x+=v.x; s.y+=v.y; s.z+=v.z; s.w+=v.w;
    }
  } else {
    const int j = i - P_*H_;
    #pragma unroll
    for (int z = 0; z < 8; ++z){
      float4 v = *(const float4*)(partD + (size_t)z*((size_t)D_*H_) + j);
      s.x+=v.x; s.y+=v.y; s.z+=v.z; s.w+=v.w;
    }
  }
  const float4 b = *(const float4*)(bias + (i & (H_-1)));
  s.x+=b.x; s.y+=b.y; s.z+=b.z; s.w+=b.w;
  s.x = (s.x>=0.f)? s.x : 0.1f*s.x;
  s.y = (s.y>=0.f)? s.y : 0.1f*s.y;
  s.z = (s.z>=0.f)? s.z : 0.1f*s.z;
  s.w = (s.w>=0.f)? s.w : 0.1f*s.w;
  *(float4*)(out + i) = s;
}

extern "C" void kernel_launch(void* const* d_in, const int* in_sizes, int n_in,
                              void* d_out, int out_size, void* d_ws, size_t ws_size,
                              hipStream_t stream){
  (void)in_sizes; (void)n_in; (void)out_size; (void)ws_size;
  const float* p_feat = (const float*)d_in[0];
  const float* d_feat = (const float*)d_in[1];
  const float* S      = (const float*)d_in[4];
  const float* pw     = (const float*)d_in[5];
  const float* bias   = (const float*)d_in[6];
  float* out = (float*)d_out;

  char* ws = (char*)d_ws;
  __bf16* wct    = (__bf16*)(ws + 0);           //  1,310,720
  __bf16* Tdt    = (__bf16*)(ws + 1310720);     // 10,485,760
  __bf16* Tpt    = (__bf16*)(ws + 11796480);    //  5,242,880
  float*  rs     = (float*) (ws + 17039360);    //     40,960
  float*  cs     = (float*) (ws + 17080320);    //     81,920
  float*  cspart = (float*) (ws + 17162240);    //  5,242,880 (64 slices)
  __bf16* Sbf    = (__bf16*)(ws + 22405120);    // 83,886,080
  float*  partP  = (float*) (ws + 106291200);   // 33,554,432 (16 slices)
  float*  partD  = (float*) (ws + 139845632);   // 33,554,432 (8 slices)
                                                // end: 173,400,064

  k_prep2 <<<384, 256, 0, stream>>>(S, pw, Sbf, rs, cspart, wct);
  k_csfin <<<(R_*D_)/256, 256, 0, stream>>>(cspart, cs);
  k_tmp   <<<dim3((P_+D_)/64, R_), 256, 0, stream>>>(p_feat, d_feat, rs, cs, wct, Tpt, Tdt);
  k_z     <<<512, 512, 0, stream>>>(Sbf, rs, cs, Tdt, Tpt, partP, partD);
  k_reduce<<<((P_+D_)*H_)/1024, 256, 0, stream>>>(partP, partD, bias, out);
}

// Round 12
// 180.821 us; speedup vs baseline: 1.7741x; 1.0393x over previous
//
#include <hip/hip_runtime.h>

typedef __bf16 bf16x8 __attribute__((ext_vector_type(8)));
typedef __bf16 bf16x4 __attribute__((ext_vector_type(4)));
typedef float  f32x4  __attribute__((ext_vector_type(4)));

#define P_  2048
#define D_  4096
#define IC_ 512
#define H_  256
#define R_  5
#define KP_ (R_*D_)   /* 20480 : K for z_p  (r,d) */
#define KD_ (R_*P_)   /* 10240 : K for z_d  (r,p) */

// LDS k-slot swizzle (validated r2-r4)
__device__ __forceinline__ int swzf(int row){ return ((row>>1) ^ (row>>3)) & 3; }

__device__ __forceinline__ bf16x8 cvt8(float4 a, float4 b){
  bf16x8 o;
  o[0]=(__bf16)a.x; o[1]=(__bf16)a.y; o[2]=(__bf16)a.z; o[3]=(__bf16)a.w;
  o[4]=(__bf16)b.x; o[5]=(__bf16)b.y; o[6]=(__bf16)b.z; o[7]=(__bf16)b.w;
  return o;
}

__device__ __forceinline__ void gl_lds16(const __bf16* g, __bf16* l){
  __builtin_amdgcn_global_load_lds(
    (const __attribute__((address_space(1))) unsigned int*)(g),
    (__attribute__((address_space(3))) unsigned int*)(l), 16, 0, 0);
}

// ---------------- K1: fused wcum + prep. blocks [0,320): prep slab; [320,384): wcum ----------------
__global__ __launch_bounds__(256) void k_prep2(const float* __restrict__ S,
    const float* __restrict__ pw, __bf16* __restrict__ Sbf, float* __restrict__ rs,
    float* __restrict__ cspart, __bf16* __restrict__ wct){
  __shared__ float wsum[32][4];
  const int t = threadIdx.x;
  if (blockIdx.x >= 320){
    const int h  = t;
    const int i0 = (blockIdx.x - 320) * 8;
    float acc[8];
    #pragma unroll
    for (int j=0;j<8;++j) acc[j]=0.f;
    for (int r=0;r<R_;++r){
      bf16x8 o;
      #pragma unroll
      for (int j=0;j<8;++j){
        acc[j] += pw[((size_t)r*IC_ + i0 + j)*H_ + h];
        o[j] = (__bf16)acc[j];
      }
      *reinterpret_cast<bf16x8*>(wct + ((size_t)r*H_ + h)*IC_ + i0) = o;
    }
    return;
  }
  const int lane = t & 63, w = t >> 6;
  const int slab = blockIdx.x;
  const int r = slab >> 6, z = slab & 63;
  const size_t row0 = (size_t)r*P_ + (size_t)z*32;
  const float4* src = reinterpret_cast<const float4*>(S + row0*D_);
  __bf16* dst = Sbf + row0*D_;
  f32x4 ca[4];
  #pragma unroll
  for (int c=0;c<4;++c){ ca[c][0]=0.f; ca[c][1]=0.f; ca[c][2]=0.f; ca[c][3]=0.f; }
  for (int pp=0; pp<32; ++pp){
    float4 v[4];
    #pragma unroll
    for (int c=0;c<4;++c) v[c] = src[(size_t)pp*(D_/4) + t + 256*c];
    float rsum = 0.f;
    #pragma unroll
    for (int c=0;c<4;++c){
      ca[c][0]+=v[c].x; ca[c][1]+=v[c].y; ca[c][2]+=v[c].z; ca[c][3]+=v[c].w;
      rsum += v[c].x+v[c].y+v[c].z+v[c].w;
      bf16x4 o; o[0]=(__bf16)v[c].x; o[1]=(__bf16)v[c].y; o[2]=(__bf16)v[c].z; o[3]=(__bf16)v[c].w;
      *reinterpret_cast<bf16x4*>(dst + (size_t)pp*D_ + (t + 256*c)*4) = o;
    }
    #pragma unroll
    for (int off = 32; off; off >>= 1) rsum += __shfl_xor(rsum, off);
    if (lane == 0) wsum[pp][w] = rsum;
  }
  __syncthreads();
  if (t < 32){
    float s = wsum[t][0]+wsum[t][1]+wsum[t][2]+wsum[t][3];
    rs[row0 + t] = (s > 0.f) ? rsqrtf(s) : 0.f;
  }
  float* o = cspart + ((size_t)z*R_ + r)*D_;
  #pragma unroll
  for (int c=0;c<4;++c) *reinterpret_cast<f32x4*>(o + (t + 256*c)*4) = ca[c];
}

__global__ void k_csfin(const float* __restrict__ cspart, float* __restrict__ cs){
  const int i = blockIdx.x*256 + threadIdx.x;
  float s = 0.f;
  #pragma unroll
  for (int z = 0; z < 64; ++z) s += cspart[(size_t)z*(R_*D_) + i];
  cs[i] = (s > 0.f) ? rsqrtf(s) : 0.f;
}

// ---------------- K5: merged tmp GEMMs (r4 2-barrier form — validated best) ----------------
__global__ __launch_bounds__(256) void k_tmp(const float* __restrict__ p_feat,
    const float* __restrict__ d_feat, const float* __restrict__ rs,
    const float* __restrict__ cs, const __bf16* __restrict__ wct,
    __bf16* __restrict__ Tpt, __bf16* __restrict__ Tdt){
  __shared__ __bf16 As[64*40];
  const int t = threadIdx.x, lane = t & 63, w = t >> 6;
  const int mt = blockIdx.x, r = blockIdx.y;
  const bool isp = mt < (P_/64);
  const float* feat  = isp ? p_feat : d_feat;
  const float* scale = isp ? rs : cs;
  __bf16* outT = isp ? Tpt : Tdt;
  const int M  = isp ? P_ : D_;
  const int RM = isp ? KD_ : KP_;
  const int m0 = (isp ? mt : mt - P_/64)*64;
  const int srow = t >> 2, skc = (t & 3)*8;
  f32x4 acc[4][4];
  #pragma unroll
  for (int a=0;a<4;++a)
    #pragma unroll
    for (int b=0;b<4;++b){ acc[a][b][0]=0.f; acc[a][b][1]=0.f; acc[a][b][2]=0.f; acc[a][b][3]=0.f; }

  for (int ks = 0; ks < IC_; ks += 32){
    __syncthreads();
    {
      const float* g = feat + (size_t)(m0+srow)*IC_ + ks + skc;
      float4 a = *(const float4*)g, b = *(const float4*)(g+4);
      *reinterpret_cast<bf16x8*>(&As[srow*40 + skc]) = cvt8(a,b);
    }
    __syncthreads();
    bf16x8 af[4], bfv[4];
    #pragma unroll
    for (int tt=0;tt<4;++tt)
      af[tt] = *reinterpret_cast<const bf16x8*>(&As[(16*tt + (lane&15))*40 + (lane>>4)*8]);
    #pragma unroll
    for (int cc=0;cc<4;++cc)
      bfv[cc] = *reinterpret_cast<const bf16x8*>(wct + ((size_t)r*H_ + w*64 + 16*cc + (lane&15))*IC_ + ks + (lane>>4)*8);
    #pragma unroll
    for (int tt=0;tt<4;++tt)
      #pragma unroll
      for (int cc=0;cc<4;++cc)
        acc[tt][cc] = __builtin_amdgcn_mfma_f32_16x16x32_bf16(af[tt], bfv[cc], acc[tt][cc], 0, 0, 0);
  }
  #pragma unroll
  for (int tt=0;tt<4;++tt){
    const int mb = m0 + 16*tt + ((lane>>4)<<2);
    const float s0 = scale[r*M+mb+0], s1 = scale[r*M+mb+1],
                s2 = scale[r*M+mb+2], s3 = scale[r*M+mb+3];
    #pragma unroll
    for (int cc=0;cc<4;++cc){
      const int hc = (w<<6) + 16*cc + (lane&15);
      bf16x4 v;
      v[0]=(__bf16)(acc[tt][cc][0]*s0); v[1]=(__bf16)(acc[tt][cc][1]*s1);
      v[2]=(__bf16)(acc[tt][cc][2]*s2); v[3]=(__bf16)(acc[tt][cc][3]*s3);
      *reinterpret_cast<bf16x4*>(outT + (size_t)hc*RM + r*M + mb) = v;
    }
  }
}

// ---------------- K6: merged z GEMM — r4-EXACT structure + XCD bid remap (r11-validated) ----------------
// Partials now bf16 (halves partial write traffic; precision margin 20x).
__global__ __launch_bounds__(512, 4) void k_z(const __bf16* __restrict__ Sbf,
    const float* __restrict__ rs, const float* __restrict__ cs,
    const __bf16* __restrict__ Tdt, const __bf16* __restrict__ Tpt,
    __bf16* __restrict__ partP, __bf16* __restrict__ partD){
  __shared__ __bf16 As[128*32];   // swizzled [row][slot*8+off]
  __shared__ __bf16 Bs[256*32];
  const int t = threadIdx.x, lane = t & 63, w = t >> 6;
  const int wm = w >> 2, wn = w & 3;
  const int bid = ((blockIdx.x & 7) << 6) | (blockIdx.x >> 3);  // bijective, 512=8*64
  const bool isp = bid < 256;
  const int tile  = isp ? (bid & 15) : ((bid-256) & 31);
  const int split = isp ? (bid >> 4) : ((bid-256) >> 5);
  const int m0 = tile*128;
  const int kbase = split*1280;
  const __bf16* Bsrc = isp ? Tdt : Tpt;
  const int bstr = isp ? KP_ : KD_;
  // zp A-staging indices
  const int arow  = t >> 2;
  const int aslot = (t & 3) ^ swzf(arow);
  // zd A-staging indices
  const int prow = t >> 4, d8 = (t & 15)*8;
  // B-staging (common)
  const int brow0 = t >> 2, brow1 = 128 + brow0;
  const int bko0 = ((t & 3) ^ swzf(brow0)) * 8;
  const int bko1 = ((t & 3) ^ swzf(brow1)) * 8;
  __bf16* bdst0 = Bs + w*512;
  __bf16* bdst1 = Bs + 4096 + w*512;
  f32x4 acc[4][4];
  #pragma unroll
  for (int a=0;a<4;++a)
    #pragma unroll
    for (int b=0;b<4;++b){ acc[a][b][0]=0.f; acc[a][b][1]=0.f; acc[a][b][2]=0.f; acc[a][b][3]=0.f; }

  for (int ko = 0; ko < 1280; ko += 32){
    const int kg = kbase + ko;
    __syncthreads();
    if (isp){
      const int r = kg >> 12, dd = kg & (D_-1);   // 32-step never straddles r
      const __bf16* g = Sbf + ((size_t)r*P_ + m0 + arow)*D_ + dd + (t&3)*8;
      const float sc = rs[r*P_ + m0 + arow];
      bf16x8 v = *reinterpret_cast<const bf16x8*>(g);
      bf16x8 o;
      #pragma unroll
      for (int j=0;j<8;++j) o[j] = (__bf16)((float)v[j] * sc);
      *reinterpret_cast<bf16x8*>(&As[arow*32 + aslot*8]) = o;
    } else {
      const int r = kg >> 11, pp = kg & (P_-1);
      const __bf16* g = Sbf + ((size_t)r*P_ + pp + prow)*D_ + m0 + d8;
      bf16x8 v = *reinterpret_cast<const bf16x8*>(g);
      const float4 c1 = *(const float4*)(cs + r*D_ + m0 + d8);
      const float4 c2 = *(const float4*)(cs + r*D_ + m0 + d8 + 4);
      bf16x8 o;
      o[0]=(__bf16)((float)v[0]*c1.x); o[1]=(__bf16)((float)v[1]*c1.y);
      o[2]=(__bf16)((float)v[2]*c1.z); o[3]=(__bf16)((float)v[3]*c1.w);
      o[4]=(__bf16)((float)v[4]*c2.x); o[5]=(__bf16)((float)v[5]*c2.y);
      o[6]=(__bf16)((float)v[6]*c2.z); o[7]=(__bf16)((float)v[7]*c2.w);
      const int kqw = prow >> 3, koff = prow & 7;
      #pragma unroll
      for (int j=0;j<8;++j){
        const int rowd = d8 + j;
        As[rowd*32 + ((kqw ^ swzf(rowd))<<3) + koff] = o[j];
      }
    }
    gl_lds16(Bsrc + (size_t)brow0*bstr + kg + bko0, bdst0);
    gl_lds16(Bsrc + (size_t)brow1*bstr + kg + bko1, bdst1);
    __syncthreads();
    const int kq = lane >> 4;
    bf16x8 bv[4];
    #pragma unroll
    for (int cc=0;cc<4;++cc){
      const int row = wn*64 + 16*cc + (lane&15);
      bv[cc] = *reinterpret_cast<const bf16x8*>(&Bs[row*32 + ((kq ^ swzf(row))<<3)]);
    }
    #pragma unroll
    for (int tt=0;tt<4;++tt){
      const int row = wm*64 + 16*tt + (lane&15);
      bf16x8 af = *reinterpret_cast<const bf16x8*>(&As[row*32 + ((kq ^ swzf(row))<<3)]);
      #pragma unroll
      for (int cc=0;cc<4;++cc)
        acc[tt][cc] = __builtin_amdgcn_mfma_f32_16x16x32_bf16(af, bv[cc], acc[tt][cc], 0, 0, 0);
    }
  }
  __bf16* o = isp ? (partP + (size_t)split*((size_t)P_*H_))
                  : (partD + (size_t)split*((size_t)D_*H_));
  #pragma unroll
  for (int tt=0;tt<4;++tt){
    const int mb = m0 + wm*64 + 16*tt + ((lane>>4)<<2);
    #pragma unroll
    for (int cc=0;cc<4;++cc){
      const int hc = wn*64 + 16*cc + (lane&15);
      #pragma unroll
      for (int j=0;j<4;++j) o[(size_t)(mb+j)*H_ + hc] = (__bf16)acc[tt][cc][j];
    }
  }
}

// ---------------- K7: merged reduce (bf16 partials) + bias + LeakyReLU ----------------
__global__ void k_reduce(const __bf16* __restrict__ partP, const __bf16* __restrict__ partD,
    const float* __restrict__ bias, float* __restrict__ out){
  const int i = (blockIdx.x*256 + threadIdx.x)*4;
  float4 s; s.x=s.y=s.z=s.w=0.f;
  if (i < P_*H_){
    #pragma unroll
    for (int z = 0; z < 16; ++z){
      bf16x4 v = *reinterpret_cast<const bf16x4*>(partP + (size_t)z*((size_t)P_*H_) + i);
      s.x+=(float)v[0]; s.y+=(float)v[1]; s.z+=(float)v[2]; s.w+=(float)v[3];
    }
  } else {
    const int j = i - P_*H_;
    #pragma unroll
    for (int z = 0; z < 8; ++z){
      bf16x4 v = *reinterpret_cast<const bf16x4*>(partD + (size_t)z*((size_t)D_*H_) + j);
      s.x+=(float)v[0]; s.y+=(float)v[1]; s.z+=(float)v[2]; s.w+=(float)v[3];
    }
  }
  const float4 b = *(const float4*)(bias + (i & (H_-1)));
  s.x+=b.x; s.y+=b.y; s.z+=b.z; s.w+=b.w;
  s.x = (s.x>=0.f)? s.x : 0.1f*s.x;
  s.y = (s.y>=0.f)? s.y : 0.1f*s.y;
  s.z = (s.z>=0.f)? s.z : 0.1f*s.z;
  s.w = (s.w>=0.f)? s.w : 0.1f*s.w;
  *(float4*)(out + i) = s;
}

extern "C" void kernel_launch(void* const* d_in, const int* in_sizes, int n_in,
                              void* d_out, int out_size, void* d_ws, size_t ws_size,
                              hipStream_t stream){
  (void)in_sizes; (void)n_in; (void)out_size; (void)ws_size;
  const float* p_feat = (const float*)d_in[0];
  const float* d_feat = (const float*)d_in[1];
  const float* S      = (const float*)d_in[4];
  const float* pw     = (const float*)d_in[5];
  const float* bias   = (const float*)d_in[6];
  float* out = (float*)d_out;

  char* ws = (char*)d_ws;
  __bf16* wct    = (__bf16*)(ws + 0);           //  1,310,720
  __bf16* Tdt    = (__bf16*)(ws + 1310720);     // 10,485,760
  __bf16* Tpt    = (__bf16*)(ws + 11796480);    //  5,242,880
  float*  rs     = (float*) (ws + 17039360);    //     40,960
  float*  cs     = (float*) (ws + 17080320);    //     81,920
  float*  cspart = (float*) (ws + 17162240);    //  5,242,880 (64 slices)
  __bf16* Sbf    = (__bf16*)(ws + 22405120);    // 83,886,080
  __bf16* partP  = (__bf16*)(ws + 106291200);   // 16,777,216 (16 slices, bf16)
  __bf16* partD  = (__bf16*)(ws + 123068416);   // 16,777,216 (8 slices, bf16)
                                                // end: 139,845,632

  k_prep2 <<<384, 256, 0, stream>>>(S, pw, Sbf, rs, cspart, wct);
  k_csfin <<<(R_*D_)/256, 256, 0, stream>>>(cspart, cs);
  k_tmp   <<<dim3((P_+D_)/64, R_), 256, 0, stream>>>(p_feat, d_feat, rs, cs, wct, Tpt, Tdt);
  k_z     <<<512, 512, 0, stream>>>(Sbf, rs, cs, Tdt, Tpt, partP, partD);
  k_reduce<<<((P_+D_)*H_)/1024, 256, 0, stream>>>(partP, partD, bias, out);
}